// Round 1
// baseline (182.540 us; speedup 1.0000x reference)
//
#include <hip/hip_runtime.h>
#include <cstdint>

#define N_PROP 65536
#define N_GT 64
#define NUM_CLASSES 81
#define TOTAL_SLOTS 512
#define MAX_POS 128

// ---------------------------------------------------------------------------
// Kernel 1: per-proposal max-IoU vs 64 GT boxes, argmax gt index, category.
// code_ws[i] = (cat << 8) | gt_idx ; cat: 2=pos(>=0.5), 1=neg([0.1,0.5)), 0=ignore
// IoU expression has no FMA-contraction sites -> bitwise matches NumPy fp32,
// so the threshold compares and argmax are exact.
// ---------------------------------------------------------------------------
__global__ __launch_bounds__(256) void iou_cat_kernel(
    const float* __restrict__ props,
    const float* __restrict__ gts,
    int* __restrict__ code_ws) {
  __shared__ float4 sgt[N_GT];
  __shared__ float sarea[N_GT];
  int tid = threadIdx.x;
  if (tid < N_GT) {
    float4 g = ((const float4*)gts)[tid];
    sgt[tid] = g;
    sarea[tid] = (g.z - g.x) * (g.w - g.y);
  }
  __syncthreads();
  int i = blockIdx.x * blockDim.x + tid;
  if (i >= N_PROP) return;
  float4 p = ((const float4*)props)[i];
  float area_a = (p.z - p.x) * (p.w - p.y);
  float best = -1.0f;
  int bg = 0;
  for (int g = 0; g < N_GT; ++g) {
    float4 q = sgt[g];
    float ltx = fmaxf(p.x, q.x);
    float lty = fmaxf(p.y, q.y);
    float rbx = fminf(p.z, q.z);
    float rby = fminf(p.w, q.w);
    float wx = fmaxf(rbx - ltx, 0.0f);
    float wy = fmaxf(rby - lty, 0.0f);
    float inter = wx * wy;
    float denom = area_a + sarea[g] - inter + 1e-8f;
    float iou = inter / denom;
    if (iou > best) { best = iou; bg = g; }  // strict > keeps FIRST max (jnp.argmax)
  }
  int cat = (best >= 0.5f) ? 2 : ((best >= 0.1f) ? 1 : 0);
  code_ws[i] = (cat << 8) | bg;
}

// ---------------------------------------------------------------------------
// Kernel 2 (single block, 1024 threads):
//  Phase A: ordered selection. Collect first 128 pos indices (ascending),
//           first 512 neg indices, first 512 non-neg indices (for the
//           neg_order overflow case). Ordered block scan via wave ballots.
//  Phase B: threads 0..511 compute per-slot CE + smooth-L1; block-reduce.
// ---------------------------------------------------------------------------
__global__ __launch_bounds__(1024) void select_loss_kernel(
    const float* __restrict__ props,
    const float* __restrict__ scores,
    const float* __restrict__ deltas,
    const float* __restrict__ gts,
    const int* __restrict__ gt_labels,
    const int* __restrict__ code_ws,
    float* __restrict__ out) {
  __shared__ int pos_list[MAX_POS];
  __shared__ int neg_list[TOTAL_SLOTS];
  __shared__ int nn_list[TOTAL_SLOTS];
  __shared__ int wsum_p[16], wsum_n[16], wsum_nn[16];
  __shared__ int base_p, base_n, base_nn;
  __shared__ float red[1024];
  __shared__ float ce_sum_sh;

  int tid = threadIdx.x;
  if (tid == 0) { base_p = 0; base_n = 0; base_nn = 0; }
  __syncthreads();

  int lane = tid & 63;
  int wave = tid >> 6;
  uint64_t lmask = (1ULL << lane) - 1ULL;

  for (int c = 0; c < N_PROP / 1024; ++c) {
    // early exit once all three banks are full (uniform branch, after sync)
    if (base_p >= MAX_POS && base_n >= TOTAL_SLOTS && base_nn >= TOTAL_SLOTS)
      break;
    int i = c * 1024 + tid;
    int code = code_ws[i];
    int cat = code >> 8;
    bool isp = (cat == 2);
    bool isn = (cat == 1);
    bool isnn = !isn;  // neg_order's tail = all non-neg indices ascending
    uint64_t bp = __ballot(isp);
    uint64_t bn = __ballot(isn);
    uint64_t bnn = __ballot(isnn);
    if (lane == 0) {
      wsum_p[wave] = __popcll(bp);
      wsum_n[wave] = __popcll(bn);
      wsum_nn[wave] = __popcll(bnn);
    }
    __syncthreads();
    int wp = 0, wn = 0, wnn = 0;
    for (int w = 0; w < wave; ++w) {
      wp += wsum_p[w];
      wn += wsum_n[w];
      wnn += wsum_nn[w];
    }
    if (isp) {
      int r = base_p + wp + __popcll(bp & lmask);
      if (r < MAX_POS) pos_list[r] = i;
    }
    if (isn) {
      int r = base_n + wn + __popcll(bn & lmask);
      if (r < TOTAL_SLOTS) neg_list[r] = i;
    }
    if (isnn) {
      int r = base_nn + wnn + __popcll(bnn & lmask);
      if (r < TOTAL_SLOTS) nn_list[r] = i;
    }
    __syncthreads();
    if (tid == 0) {
      int tp = 0, tn = 0, tnn = 0;
      for (int w = 0; w < 16; ++w) {
        tp += wsum_p[w];
        tn += wsum_n[w];
        tnn += wsum_nn[w];
      }
      base_p += tp;
      base_n += tn;
      base_nn += tnn;
    }
    __syncthreads();
  }

  int num_pos = min(base_p, MAX_POS);
  int neg_total = base_n;  // exact when < TOTAL_SLOTS (overflow case); else only
                           // ">= slot count" matters

  float ce = 0.0f, reg = 0.0f;
  if (tid < TOTAL_SLOTS) {
    int s = tid;
    bool is_pos = (s < num_pos);
    int i;
    if (is_pos) {
      i = pos_list[s];
    } else {
      int j = s - num_pos;
      i = (j < neg_total) ? neg_list[j] : nn_list[j - neg_total];
    }
    int g = code_ws[i] & 0xFF;

    // ---- classification CE (log-softmax over 81 classes) ----
    int cls = is_pos ? gt_labels[g] : 0;
    const float* row = scores + (size_t)i * NUM_CLASSES;
    float m = -INFINITY;
    for (int k = 0; k < NUM_CLASSES; ++k) m = fmaxf(m, row[k]);
    float sum = 0.0f;
    for (int k = 0; k < NUM_CLASSES; ++k) sum += expf(row[k] - m);
    ce = -(row[cls] - m - logf(sum));

    // ---- regression smooth-L1 (masked by is_pos) ----
    const float* pr = props + 4 * i;
    float pw = pr[2] - pr[0];
    float ph = pr[3] - pr[1];
    float pcx = pr[0] + 0.5f * pw;
    float pcy = pr[1] + 0.5f * ph;
    const float* gb = gts + 4 * g;
    float gw = gb[2] - gb[0];
    float gh = gb[3] - gb[1];
    float gcx = gb[0] + 0.5f * gw;
    float gcy = gb[1] + 0.5f * gh;
    float t0 = ((gcx - pcx) / pw) / 0.1f;
    float t1 = ((gcy - pcy) / ph) / 0.1f;
    float t2 = logf(gw / pw) / 0.2f;
    float t3 = logf(gh / ph) / 0.2f;
    const float* dd = deltas + ((size_t)i * NUM_CLASSES + (size_t)g) * 4;
    float d0 = dd[0] - t0;
    float d1 = dd[1] - t1;
    float d2 = dd[2] - t2;
    float d3 = dd[3] - t3;
    float sl = 0.0f;
    float a;
    a = fabsf(d0); sl += (a < 1.0f) ? 0.5f * d0 * d0 : a - 0.5f;
    a = fabsf(d1); sl += (a < 1.0f) ? 0.5f * d1 * d1 : a - 0.5f;
    a = fabsf(d2); sl += (a < 1.0f) ? 0.5f * d2 * d2 : a - 0.5f;
    a = fabsf(d3); sl += (a < 1.0f) ? 0.5f * d3 * d3 : a - 0.5f;
    if (is_pos) reg = sl;
  }

  // ---- block reduction (1024 threads; tids >= 512 contribute 0) ----
  red[tid] = ce;
  __syncthreads();
  for (int off = 512; off >= 1; off >>= 1) {
    if (tid < off) red[tid] += red[tid + off];
    __syncthreads();
  }
  if (tid == 0) ce_sum_sh = red[0];
  __syncthreads();

  red[tid] = reg;
  __syncthreads();
  for (int off = 512; off >= 1; off >>= 1) {
    if (tid < off) red[tid] += red[tid + off];
    __syncthreads();
  }
  if (tid == 0) {
    out[0] = ce_sum_sh / (float)TOTAL_SLOTS;   // CLS_W = 1
    out[1] = red[0] / (float)TOTAL_SLOTS;      // REG_W = 1
  }
}

extern "C" void kernel_launch(void* const* d_in, const int* in_sizes, int n_in,
                              void* d_out, int out_size, void* d_ws, size_t ws_size,
                              hipStream_t stream) {
  (void)in_sizes; (void)n_in; (void)out_size; (void)ws_size;
  // input order per setup_inputs():
  // 0: image_shape (unused), 1: rpn_proposals_bboxes (65536,4),
  // 2: roi_score (65536,81), 3: roi_bboxes_txtytwth (65536,81,4),
  // 4: gt_bboxes (64,4), 5: gt_labels (64,) int32
  const float* props = (const float*)d_in[1];
  const float* scores = (const float*)d_in[2];
  const float* deltas = (const float*)d_in[3];
  const float* gts = (const float*)d_in[4];
  const int* gt_labels = (const int*)d_in[5];
  float* out = (float*)d_out;
  int* code_ws = (int*)d_ws;  // 65536 ints

  iou_cat_kernel<<<N_PROP / 256, 256, 0, stream>>>(props, gts, code_ws);
  select_loss_kernel<<<1, 1024, 0, stream>>>(props, scores, deltas, gts,
                                             gt_labels, code_ws, out);
}

// Round 2
// 149.586 us; speedup vs baseline: 1.2203x; 1.2203x over previous
//
#include <hip/hip_runtime.h>
#include <cstdint>

#define N_PROP 65536
#define N_GT 64
#define NUM_CLASSES 81
#define TOTAL_SLOTS 512
#define MAX_POS 128

// ---------------------------------------------------------------------------
// Kernel 1: per-proposal max-IoU vs 64 GT boxes, argmax gt index, category.
// code_ws[i] = (cat << 8) | gt_idx ; cat: 2=pos(>=0.5), 1=neg([0.1,0.5)), 0=ignore
// IoU expression has no FMA-contraction sites -> bitwise matches NumPy fp32,
// so the threshold compares and argmax are exact.
// ---------------------------------------------------------------------------
__global__ __launch_bounds__(256) void iou_cat_kernel(
    const float* __restrict__ props,
    const float* __restrict__ gts,
    int* __restrict__ code_ws) {
  __shared__ float4 sgt[N_GT];
  __shared__ float sarea[N_GT];
  int tid = threadIdx.x;
  if (tid < N_GT) {
    float4 g = ((const float4*)gts)[tid];
    sgt[tid] = g;
    sarea[tid] = (g.z - g.x) * (g.w - g.y);
  }
  __syncthreads();
  int i = blockIdx.x * blockDim.x + tid;
  float4 p = ((const float4*)props)[i];
  float area_a = (p.z - p.x) * (p.w - p.y);
  float best = -1.0f;
  int bg = 0;
  for (int g = 0; g < N_GT; ++g) {
    float4 q = sgt[g];
    float ltx = fmaxf(p.x, q.x);
    float lty = fmaxf(p.y, q.y);
    float rbx = fminf(p.z, q.z);
    float rby = fminf(p.w, q.w);
    float wx = fmaxf(rbx - ltx, 0.0f);
    float wy = fmaxf(rby - lty, 0.0f);
    float inter = wx * wy;
    float denom = area_a + sarea[g] - inter + 1e-8f;
    float iou = inter / denom;
    if (iou > best) { best = iou; bg = g; }  // strict > keeps FIRST max (jnp.argmax)
  }
  int cat = (best >= 0.5f) ? 2 : ((best >= 0.1f) ? 1 : 0);
  code_ws[i] = (cat << 8) | bg;
}

// ---------------------------------------------------------------------------
// Kernel 2 (single block, 1024 threads): ordered selection ONLY.
// Collect first 128 pos indices (ascending), first 512 neg, first 512 non-neg
// (neg_order overflow). Emit 512 slot descriptors (idx | gt<<17 | pos<<23)
// and zero d_out for kernel 3's atomics.
// ---------------------------------------------------------------------------
__global__ __launch_bounds__(1024) void select_kernel(
    const int* __restrict__ code_ws,
    int* __restrict__ sel_ws,
    float* __restrict__ out) {
  __shared__ int pos_list[MAX_POS];
  __shared__ int neg_list[TOTAL_SLOTS];
  __shared__ int nn_list[TOTAL_SLOTS];
  __shared__ int wsum_p[16], wsum_n[16], wsum_nn[16];
  __shared__ int base_p, base_n, base_nn;

  int tid = threadIdx.x;
  if (tid == 0) { base_p = 0; base_n = 0; base_nn = 0; }
  __syncthreads();

  int lane = tid & 63;
  int wave = tid >> 6;
  uint64_t lmask = (1ULL << lane) - 1ULL;

  for (int c = 0; c < N_PROP / 1024; ++c) {
    if (base_p >= MAX_POS && base_n >= TOTAL_SLOTS && base_nn >= TOTAL_SLOTS)
      break;
    int i = c * 1024 + tid;
    int code = code_ws[i];
    int cat = code >> 8;
    bool isp = (cat == 2);
    bool isn = (cat == 1);
    bool isnn = !isn;
    uint64_t bp = __ballot(isp);
    uint64_t bn = __ballot(isn);
    uint64_t bnn = __ballot(isnn);
    if (lane == 0) {
      wsum_p[wave] = __popcll(bp);
      wsum_n[wave] = __popcll(bn);
      wsum_nn[wave] = __popcll(bnn);
    }
    __syncthreads();
    int wp = 0, wn = 0, wnn = 0;
    for (int w = 0; w < wave; ++w) {
      wp += wsum_p[w];
      wn += wsum_n[w];
      wnn += wsum_nn[w];
    }
    if (isp) {
      int r = base_p + wp + __popcll(bp & lmask);
      if (r < MAX_POS) pos_list[r] = i;
    }
    if (isn) {
      int r = base_n + wn + __popcll(bn & lmask);
      if (r < TOTAL_SLOTS) neg_list[r] = i;
    }
    if (isnn) {
      int r = base_nn + wnn + __popcll(bnn & lmask);
      if (r < TOTAL_SLOTS) nn_list[r] = i;
    }
    __syncthreads();
    if (tid == 0) {
      int tp = 0, tn = 0, tnn = 0;
      for (int w = 0; w < 16; ++w) {
        tp += wsum_p[w];
        tn += wsum_n[w];
        tnn += wsum_nn[w];
      }
      base_p += tp;
      base_n += tn;
      base_nn += tnn;
    }
    __syncthreads();
  }

  int num_pos = min(base_p, MAX_POS);
  int neg_total = base_n;

  if (tid < TOTAL_SLOTS) {
    int s = tid;
    bool is_pos = (s < num_pos);
    int i;
    if (is_pos) {
      i = pos_list[s];
    } else {
      int j = s - num_pos;
      i = (j < neg_total) ? neg_list[j] : nn_list[j - neg_total];
    }
    int g = code_ws[i] & 0xFF;
    sel_ws[s] = i | (g << 17) | ((is_pos ? 1 : 0) << 23);
  }
  if (tid < 2) out[tid] = 0.0f;
}

// ---------------------------------------------------------------------------
// Kernel 3: one wave per slot (512 blocks x 64 threads).
// Coalesced 81-class row read, shfl-butterfly max & exp-sum, lane0 does CE +
// smooth-L1 and atomicAdds the pre-scaled partials into out[0..1].
// ---------------------------------------------------------------------------
__global__ __launch_bounds__(64) void loss_kernel(
    const float* __restrict__ props,
    const float* __restrict__ scores,
    const float* __restrict__ deltas,
    const float* __restrict__ gts,
    const int* __restrict__ gt_labels,
    const int* __restrict__ sel_ws,
    float* __restrict__ out) {
  int s = blockIdx.x;
  int packed = sel_ws[s];
  int i = packed & 0x1FFFF;
  int g = (packed >> 17) & 0x3F;
  bool is_pos = (packed >> 23) & 1;

  int lane = threadIdx.x;
  const float* row = scores + (size_t)i * NUM_CLASSES;
  float v1 = row[lane];                                   // lane < 64 < 81
  bool has2 = (lane + 64) < NUM_CLASSES;                  // lanes 0..16
  float v2 = has2 ? row[lane + 64] : -INFINITY;

  float m = fmaxf(v1, v2);
  #pragma unroll
  for (int off = 32; off >= 1; off >>= 1)
    m = fmaxf(m, __shfl_xor(m, off));

  float e = __expf(v1 - m) + (has2 ? __expf(v2 - m) : 0.0f);
  #pragma unroll
  for (int off = 32; off >= 1; off >>= 1)
    e += __shfl_xor(e, off);

  if (lane == 0) {
    int cls = is_pos ? gt_labels[g] : 0;
    float ce = -(row[cls] - m - logf(e));
    atomicAdd(out + 0, ce * (1.0f / (float)TOTAL_SLOTS));

    if (is_pos) {
      const float* pr = props + 4 * i;
      float pw = pr[2] - pr[0];
      float ph = pr[3] - pr[1];
      float pcx = pr[0] + 0.5f * pw;
      float pcy = pr[1] + 0.5f * ph;
      const float* gb = gts + 4 * g;
      float gw = gb[2] - gb[0];
      float gh = gb[3] - gb[1];
      float gcx = gb[0] + 0.5f * gw;
      float gcy = gb[1] + 0.5f * gh;
      float t0 = ((gcx - pcx) / pw) / 0.1f;
      float t1 = ((gcy - pcy) / ph) / 0.1f;
      float t2 = logf(gw / pw) / 0.2f;
      float t3 = logf(gh / ph) / 0.2f;
      const float* dd = deltas + ((size_t)i * NUM_CLASSES + (size_t)g) * 4;
      float d0 = dd[0] - t0;
      float d1 = dd[1] - t1;
      float d2 = dd[2] - t2;
      float d3 = dd[3] - t3;
      float sl = 0.0f;
      float a;
      a = fabsf(d0); sl += (a < 1.0f) ? 0.5f * d0 * d0 : a - 0.5f;
      a = fabsf(d1); sl += (a < 1.0f) ? 0.5f * d1 * d1 : a - 0.5f;
      a = fabsf(d2); sl += (a < 1.0f) ? 0.5f * d2 * d2 : a - 0.5f;
      a = fabsf(d3); sl += (a < 1.0f) ? 0.5f * d3 * d3 : a - 0.5f;
      atomicAdd(out + 1, sl * (1.0f / (float)TOTAL_SLOTS));
    }
  }
}

extern "C" void kernel_launch(void* const* d_in, const int* in_sizes, int n_in,
                              void* d_out, int out_size, void* d_ws, size_t ws_size,
                              hipStream_t stream) {
  (void)in_sizes; (void)n_in; (void)out_size; (void)ws_size;
  const float* props = (const float*)d_in[1];
  const float* scores = (const float*)d_in[2];
  const float* deltas = (const float*)d_in[3];
  const float* gts = (const float*)d_in[4];
  const int* gt_labels = (const int*)d_in[5];
  float* out = (float*)d_out;
  int* code_ws = (int*)d_ws;               // 65536 ints
  int* sel_ws = code_ws + N_PROP;          // 512 ints

  iou_cat_kernel<<<N_PROP / 256, 256, 0, stream>>>(props, gts, code_ws);
  select_kernel<<<1, 1024, 0, stream>>>(code_ws, sel_ws, out);
  loss_kernel<<<TOTAL_SLOTS, 64, 0, stream>>>(props, scores, deltas, gts,
                                              gt_labels, sel_ws, out);
}

// Round 3
// 147.336 us; speedup vs baseline: 1.2389x; 1.0153x over previous
//
#include <hip/hip_runtime.h>
#include <cstdint>

#define N_PROP 65536
#define N_GT 64
#define NUM_CLASSES 81
#define TOTAL_SLOTS 512
#define MAX_POS 128

// ---------------------------------------------------------------------------
// Kernel 1: per-proposal max-IoU vs 64 GT boxes, argmax gt index, category.
// code_ws[i] = (cat << 8) | gt_idx ; cat: 2=pos(>=0.5), 1=neg([0.1,0.5)), 0=ignore
// IoU expression has no FMA-contraction sites -> bitwise matches NumPy fp32,
// so the threshold compares and argmax are exact.
// ---------------------------------------------------------------------------
__global__ __launch_bounds__(256) void iou_cat_kernel(
    const float* __restrict__ props,
    const float* __restrict__ gts,
    int* __restrict__ code_ws) {
  __shared__ float4 sgt[N_GT];
  __shared__ float sarea[N_GT];
  int tid = threadIdx.x;
  if (tid < N_GT) {
    float4 g = ((const float4*)gts)[tid];
    sgt[tid] = g;
    sarea[tid] = (g.z - g.x) * (g.w - g.y);
  }
  __syncthreads();
  int i = blockIdx.x * blockDim.x + tid;
  float4 p = ((const float4*)props)[i];
  float area_a = (p.z - p.x) * (p.w - p.y);
  float best = -1.0f;
  int bg = 0;
  for (int g = 0; g < N_GT; ++g) {
    float4 q = sgt[g];
    float ltx = fmaxf(p.x, q.x);
    float lty = fmaxf(p.y, q.y);
    float rbx = fminf(p.z, q.z);
    float rby = fminf(p.w, q.w);
    float wx = fmaxf(rbx - ltx, 0.0f);
    float wy = fmaxf(rby - lty, 0.0f);
    float inter = wx * wy;
    float denom = area_a + sarea[g] - inter + 1e-8f;
    float iou = inter / denom;
    if (iou > best) { best = iou; bg = g; }  // strict > keeps FIRST max (jnp.argmax)
  }
  int cat = (best >= 0.5f) ? 2 : ((best >= 0.1f) ? 1 : 0);
  code_ws[i] = (cat << 8) | bg;
}

// ---------------------------------------------------------------------------
// Kernel 2 (single block, 1024 threads): ordered selection.
// int4 chunks (4096 codes), ballot-ranked, 2 barriers/chunk, replicated bases.
// Ordering within a chunk is thread-major (thread t owns indices 4t..4t+3),
// so rank = base + wave_prefix + sum_j popcll(ballot_j & lanemask) + own
// earlier sub-items. Exact argsort-order selection semantics.
// ---------------------------------------------------------------------------
__global__ __launch_bounds__(1024) void select_kernel(
    const int* __restrict__ code_ws,
    int* __restrict__ sel_ws,
    float* __restrict__ out) {
  __shared__ int pos_list[MAX_POS];
  __shared__ int neg_list[TOTAL_SLOTS];
  __shared__ int nn_list[TOTAL_SLOTS];
  __shared__ int wsum_p[16], wsum_n[16], wsum_nn[16];

  int tid = threadIdx.x;
  int lane = tid & 63;
  int wave = tid >> 6;
  uint64_t lmask = (1ULL << lane) - 1ULL;

  int base_p = 0, base_n = 0, base_nn = 0;  // replicated across all threads

  const int NCHUNK = N_PROP / 4096;  // 16
  for (int c = 0; c < NCHUNK; ++c) {
    if (base_p >= MAX_POS && base_n >= TOTAL_SLOTS && base_nn >= TOTAL_SLOTS)
      break;
    int ibase = c * 4096 + tid * 4;
    int4 cd = ((const int4*)code_ws)[c * 1024 + tid];
    int c0 = cd.x >> 8, c1 = cd.y >> 8, c2 = cd.z >> 8, c3 = cd.w >> 8;

    uint64_t bp0 = __ballot(c0 == 2), bp1 = __ballot(c1 == 2),
             bp2 = __ballot(c2 == 2), bp3 = __ballot(c3 == 2);
    uint64_t bn0 = __ballot(c0 == 1), bn1 = __ballot(c1 == 1),
             bn2 = __ballot(c2 == 1), bn3 = __ballot(c3 == 1);
    uint64_t bq0 = __ballot(c0 != 1), bq1 = __ballot(c1 != 1),
             bq2 = __ballot(c2 != 1), bq3 = __ballot(c3 != 1);

    if (lane == 0) {
      wsum_p[wave] = __popcll(bp0) + __popcll(bp1) + __popcll(bp2) + __popcll(bp3);
      wsum_n[wave] = __popcll(bn0) + __popcll(bn1) + __popcll(bn2) + __popcll(bn3);
      wsum_nn[wave] = __popcll(bq0) + __popcll(bq1) + __popcll(bq2) + __popcll(bq3);
    }
    __syncthreads();

    int wp = 0, wn = 0, wnn = 0, tp = 0, tn = 0, tnn = 0;
    #pragma unroll
    for (int w = 0; w < 16; ++w) {
      int vp = wsum_p[w], vn = wsum_n[w], vq = wsum_nn[w];
      if (w < wave) { wp += vp; wn += vn; wnn += vq; }
      tp += vp; tn += vn; tnn += vq;
    }

    int rp = base_p + wp + __popcll(bp0 & lmask) + __popcll(bp1 & lmask) +
             __popcll(bp2 & lmask) + __popcll(bp3 & lmask);
    if (c0 == 2) { if (rp < MAX_POS) pos_list[rp] = ibase + 0; ++rp; }
    if (c1 == 2) { if (rp < MAX_POS) pos_list[rp] = ibase + 1; ++rp; }
    if (c2 == 2) { if (rp < MAX_POS) pos_list[rp] = ibase + 2; ++rp; }
    if (c3 == 2) { if (rp < MAX_POS) pos_list[rp] = ibase + 3; ++rp; }

    int rn = base_n + wn + __popcll(bn0 & lmask) + __popcll(bn1 & lmask) +
             __popcll(bn2 & lmask) + __popcll(bn3 & lmask);
    if (c0 == 1) { if (rn < TOTAL_SLOTS) neg_list[rn] = ibase + 0; ++rn; }
    if (c1 == 1) { if (rn < TOTAL_SLOTS) neg_list[rn] = ibase + 1; ++rn; }
    if (c2 == 1) { if (rn < TOTAL_SLOTS) neg_list[rn] = ibase + 2; ++rn; }
    if (c3 == 1) { if (rn < TOTAL_SLOTS) neg_list[rn] = ibase + 3; ++rn; }

    int rq = base_nn + wnn + __popcll(bq0 & lmask) + __popcll(bq1 & lmask) +
             __popcll(bq2 & lmask) + __popcll(bq3 & lmask);
    if (c0 != 1) { if (rq < TOTAL_SLOTS) nn_list[rq] = ibase + 0; ++rq; }
    if (c1 != 1) { if (rq < TOTAL_SLOTS) nn_list[rq] = ibase + 1; ++rq; }
    if (c2 != 1) { if (rq < TOTAL_SLOTS) nn_list[rq] = ibase + 2; ++rq; }
    if (c3 != 1) { if (rq < TOTAL_SLOTS) nn_list[rq] = ibase + 3; ++rq; }

    base_p += tp;
    base_n += tn;
    base_nn += tnn;
    __syncthreads();  // protect wsum_* rewrite + make list writes visible
  }

  int num_pos = min(base_p, MAX_POS);
  int neg_total = base_n;

  if (tid < TOTAL_SLOTS) {
    int s = tid;
    bool is_pos = (s < num_pos);
    int i;
    if (is_pos) {
      i = pos_list[s];
    } else {
      int j = s - num_pos;
      i = (j < neg_total) ? neg_list[j] : nn_list[j - neg_total];
    }
    int g = code_ws[i] & 0xFF;
    sel_ws[s] = i | (g << 17) | ((is_pos ? 1 : 0) << 23);
  }
  if (tid < 2) out[tid] = 0.0f;
}

// ---------------------------------------------------------------------------
// Kernel 3: one wave per slot (512 blocks x 64 threads).
// Coalesced 81-class row read, shfl-butterfly max & exp-sum, lane0 does CE +
// smooth-L1 and atomicAdds the pre-scaled partials into out[0..1].
// ---------------------------------------------------------------------------
__global__ __launch_bounds__(64) void loss_kernel(
    const float* __restrict__ props,
    const float* __restrict__ scores,
    const float* __restrict__ deltas,
    const float* __restrict__ gts,
    const int* __restrict__ gt_labels,
    const int* __restrict__ sel_ws,
    float* __restrict__ out) {
  int s = blockIdx.x;
  int packed = sel_ws[s];
  int i = packed & 0x1FFFF;
  int g = (packed >> 17) & 0x3F;
  bool is_pos = (packed >> 23) & 1;

  int lane = threadIdx.x;
  const float* row = scores + (size_t)i * NUM_CLASSES;
  float v1 = row[lane];                                   // lane < 64 < 81
  bool has2 = (lane + 64) < NUM_CLASSES;                  // lanes 0..16
  float v2 = has2 ? row[lane + 64] : -INFINITY;

  float m = fmaxf(v1, v2);
  #pragma unroll
  for (int off = 32; off >= 1; off >>= 1)
    m = fmaxf(m, __shfl_xor(m, off));

  float e = __expf(v1 - m) + (has2 ? __expf(v2 - m) : 0.0f);
  #pragma unroll
  for (int off = 32; off >= 1; off >>= 1)
    e += __shfl_xor(e, off);

  if (lane == 0) {
    int cls = is_pos ? gt_labels[g] : 0;
    float ce = -(row[cls] - m - logf(e));
    atomicAdd(out + 0, ce * (1.0f / (float)TOTAL_SLOTS));

    if (is_pos) {
      const float* pr = props + 4 * i;
      float pw = pr[2] - pr[0];
      float ph = pr[3] - pr[1];
      float pcx = pr[0] + 0.5f * pw;
      float pcy = pr[1] + 0.5f * ph;
      const float* gb = gts + 4 * g;
      float gw = gb[2] - gb[0];
      float gh = gb[3] - gb[1];
      float gcx = gb[0] + 0.5f * gw;
      float gcy = gb[1] + 0.5f * gh;
      float t0 = ((gcx - pcx) / pw) / 0.1f;
      float t1 = ((gcy - pcy) / ph) / 0.1f;
      float t2 = logf(gw / pw) / 0.2f;
      float t3 = logf(gh / ph) / 0.2f;
      const float* dd = deltas + ((size_t)i * NUM_CLASSES + (size_t)g) * 4;
      float d0 = dd[0] - t0;
      float d1 = dd[1] - t1;
      float d2 = dd[2] - t2;
      float d3 = dd[3] - t3;
      float sl = 0.0f;
      float a;
      a = fabsf(d0); sl += (a < 1.0f) ? 0.5f * d0 * d0 : a - 0.5f;
      a = fabsf(d1); sl += (a < 1.0f) ? 0.5f * d1 * d1 : a - 0.5f;
      a = fabsf(d2); sl += (a < 1.0f) ? 0.5f * d2 * d2 : a - 0.5f;
      a = fabsf(d3); sl += (a < 1.0f) ? 0.5f * d3 * d3 : a - 0.5f;
      atomicAdd(out + 1, sl * (1.0f / (float)TOTAL_SLOTS));
    }
  }
}

extern "C" void kernel_launch(void* const* d_in, const int* in_sizes, int n_in,
                              void* d_out, int out_size, void* d_ws, size_t ws_size,
                              hipStream_t stream) {
  (void)in_sizes; (void)n_in; (void)out_size; (void)ws_size;
  const float* props = (const float*)d_in[1];
  const float* scores = (const float*)d_in[2];
  const float* deltas = (const float*)d_in[3];
  const float* gts = (const float*)d_in[4];
  const int* gt_labels = (const int*)d_in[5];
  float* out = (float*)d_out;
  int* code_ws = (int*)d_ws;               // 65536 ints
  int* sel_ws = code_ws + N_PROP;          // 512 ints

  iou_cat_kernel<<<N_PROP / 256, 256, 0, stream>>>(props, gts, code_ws);
  select_kernel<<<1, 1024, 0, stream>>>(code_ws, sel_ws, out);
  loss_kernel<<<TOTAL_SLOTS, 64, 0, stream>>>(props, scores, deltas, gts,
                                              gt_labels, sel_ws, out);
}